// Round 10
// baseline (353.910 us; speedup 1.0000x reference)
//
#include <hip/hip_runtime.h>
#include <stdint.h>

#define TEMP      0.07f
#define BATCH     256
#define NROWS     32768
#define DIM       2048
#define KNEG      8192

typedef __attribute__((ext_vector_type(8))) short bf16x8;
typedef __attribute__((ext_vector_type(4))) float f32x4;

// ---------------------------------------------------------------- threefry2x32
__host__ __device__ inline void tf2x32(uint32_t ka, uint32_t kb,
                                       uint32_t x0, uint32_t x1,
                                       uint32_t& o0, uint32_t& o1) {
  uint32_t ks2 = ka ^ kb ^ 0x1BD11BDAu;
#define TFR(r) { x0 += x1; x1 = (x1 << r) | (x1 >> (32 - r)); x1 ^= x0; }
  x0 += ka; x1 += kb;
  TFR(13) TFR(15) TFR(26) TFR(6)
  x0 += kb;  x1 += ks2 + 1u;
  TFR(17) TFR(29) TFR(16) TFR(24)
  x0 += ks2; x1 += ka + 2u;
  TFR(13) TFR(15) TFR(26) TFR(6)
  x0 += ka;  x1 += kb + 3u;
  TFR(17) TFR(29) TFR(16) TFR(24)
  x0 += kb;  x1 += ks2 + 4u;
  TFR(13) TFR(15) TFR(26) TFR(6)
  x0 += ks2; x1 += ka + 5u;
#undef TFR
  o0 = x0; o1 = x1;
}

// partitionable threefry (JAX >= 0.4.36): bits = out0 ^ out1, counter = (0, q)
__device__ inline uint32_t ubits_at(uint32_t ka, uint32_t kb, uint32_t q) {
  uint32_t a, b; tf2x32(ka, kb, 0u, q, a, b);
  return (a ^ b) >> 9;
}

// ---------------------------------------------------------------- block reduce
__device__ inline float block_sum(float v, float* sm) {
  __syncthreads();
  const int lane = threadIdx.x & 63;
  const int w = threadIdx.x >> 6;
  const int nw = blockDim.x >> 6;
  for (int o = 32; o; o >>= 1) v += __shfl_down(v, o, 64);
  if (lane == 0) sm[w] = v;
  __syncthreads();
  if (w == 0) {
    float x = (lane < nw) ? sm[lane] : 0.f;
    for (int o = 8; o; o >>= 1) x += __shfl_down(x, o, 64);
    if (lane == 0) sm[0] = x;
  }
  __syncthreads();
  return sm[0];
}

__device__ inline uint32_t pk2(float a, float b) {  // 2x fp32 -> packed bf16 (RNE)
  uint32_t ua = __float_as_uint(a), ub = __float_as_uint(b);
  ua = (ua + 0x7FFFu + ((ua >> 16) & 1u)) >> 16;
  ub = (ub + 0x7FFFu + ((ub >> 16) & 1u)) >> 16;
  return ua | (ub << 16);
}

// -------------------------- pack f_nv into bf16 MFMA A-fragment layout (1 MB)
// Fragment tile (mt,kt): 1 KB, lane l holds rows mt*16+(l&15), k kt*32+(l>>4)*8.
__global__ __launch_bounds__(256) void cvtA(const float* __restrict__ A,
                                            uint32_t* __restrict__ Abf) {
  const int t = threadIdx.x;
  const int w = blockIdx.x * 4 + (t >> 6);   // 1024 fragment tiles
  const int l = t & 63;
  const int mt = w >> 6, kt = w & 63;
  const float* src = &A[(size_t)(mt * 16 + (l & 15)) * DIM + kt * 32 + (l >> 4) * 8];
  float4 f0 = *(const float4*)src;
  float4 f1 = *(const float4*)(src + 4);
  *(uint4*)(Abf + (size_t)w * 256 + l * 4) =
      make_uint4(pk2(f0.x, f0.y), pk2(f0.z, f0.w), pk2(f1.x, f1.y), pk2(f1.z, f1.w));
}

// ---------------- prep: stream features -> outF (fp32 nt) + fbf16 (row-major)
// 4-deep batched loads: 4 independent 16B loads in flight per thread before
// any dependent store -> 4x the memory-level parallelism of a serial chain.
__global__ __launch_bounds__(256) void prep(const float* __restrict__ src,
                                            float* __restrict__ outF,
                                            uint32_t* __restrict__ fbf16,
                                            int skip) {
  const int stride = gridDim.x * blockDim.x;          // in 16B granules
  const int total = NROWS * DIM / 4;
  const f32x4* __restrict__ s4 = (const f32x4*)src;
  int i = blockIdx.x * blockDim.x + threadIdx.x;
  for (; i + 3 * stride < total; i += 4 * stride) {
    f32x4 v0 = s4[i];
    f32x4 v1 = s4[i + stride];
    f32x4 v2 = s4[i + 2 * stride];
    f32x4 v3 = s4[i + 3 * stride];
    *(uint2*)(fbf16 + (size_t)i * 2) = make_uint2(pk2(v0[0], v0[1]), pk2(v0[2], v0[3]));
    *(uint2*)(fbf16 + (size_t)(i + stride) * 2) = make_uint2(pk2(v1[0], v1[1]), pk2(v1[2], v1[3]));
    *(uint2*)(fbf16 + (size_t)(i + 2 * stride) * 2) = make_uint2(pk2(v2[0], v2[1]), pk2(v2[2], v2[3]));
    *(uint2*)(fbf16 + (size_t)(i + 3 * stride) * 2) = make_uint2(pk2(v3[0], v3[1]), pk2(v3[2], v3[3]));
    if ((i >> 9) >= skip)
      __builtin_nontemporal_store(v0, (f32x4*)(outF + (size_t)i * 4));
    if (((i + stride) >> 9) >= skip)
      __builtin_nontemporal_store(v1, (f32x4*)(outF + (size_t)(i + stride) * 4));
    if (((i + 2 * stride) >> 9) >= skip)
      __builtin_nontemporal_store(v2, (f32x4*)(outF + (size_t)(i + 2 * stride) * 4));
    if (((i + 3 * stride) >> 9) >= skip)
      __builtin_nontemporal_store(v3, (f32x4*)(outF + (size_t)(i + 3 * stride) * 4));
  }
  for (; i < total; i += stride) {
    f32x4 v = s4[i];
    *(uint2*)(fbf16 + (size_t)i * 2) = make_uint2(pk2(v[0], v[1]), pk2(v[2], v[3]));
    if ((i >> 9) >= skip)
      __builtin_nontemporal_store(v, (f32x4*)(outF + (size_t)i * 4));
  }
}

// ------------------------------------------------------- async LDS staging DMA
__device__ inline void gll16(const uint32_t* g, uint32_t* l) {
  __builtin_amdgcn_global_load_lds(
      (const __attribute__((address_space(1))) uint32_t*)g,
      (__attribute__((address_space(3))) uint32_t*)l, 16, 0, 0);
}

// ------------------- m97-shape bf16 GEMM: B from L3-hot fbf16 via gll
// BM=128 x BN=64 x BK=64 bf16 -> 1024 blocks, 4 blocks/CU (8 KiB LDS each).
// Single-buffered 2-barrier loop; cross-block TLP hides the barrier drain.
__global__ __launch_bounds__(256, 4) void gemm_bf(
    const uint32_t* __restrict__ Abf,    // packed f_nv bf16 A-fragments
    const uint32_t* __restrict__ fbf16,  // features bf16 [32768][2048]
    float* __restrict__ C) {             // mat_sim [256][32768]
  __shared__ uint32_t Bs[64 * 32];       // 8 KiB: 64 rows x 128 B
  const int t = threadIdx.x;
  const int l = t & 63, w = t >> 6;
  const int bm = blockIdx.x & 1;
  const int bn = blockIdx.x >> 1;
  const int wr = w >> 1, wc = w & 1;     // 2x2 waves: 64x32 out each

  f32x4 acc[4][2] = {};

  for (int t0 = 0; t0 < DIM / 64; ++t0) {
    __syncthreads();                     // previous tile consumed
#pragma unroll
    for (int i = 0; i < 2; ++i) {
      const int ii = w * 2 + i;                  // 8 x 1KB DMAs
      const int r = ii * 8 + (l >> 3);           // tile row 0..63
      const int g = (l & 7) ^ (r & 7);           // src granule for LDS slot l&7
      gll16(&fbf16[(size_t)(bn * 64 + r) * (DIM / 2) + t0 * 32 + g * 4],
            &Bs[ii * 256]);
    }
    __syncthreads();                     // tile ready (compiler drains vmcnt)
#pragma unroll
    for (int kk = 0; kk < 2; ++kk) {
      bf16x8 af[4];
#pragma unroll
      for (int m = 0; m < 4; ++m)
        af[m] = *(const bf16x8*)(Abf +
            ((size_t)((bm * 8 + wr * 4 + m) * 64 + t0 * 2 + kk) * 64 + l) * 4);
      bf16x8 bfr[2];
#pragma unroll
      for (int n = 0; n < 2; ++n) {
        const int R = wc * 32 + n * 16 + (l & 15);
        const int slot = (kk * 4 + (l >> 4)) ^ (R & 7);
        bfr[n] = *(const bf16x8*)&Bs[R * 32 + slot * 4];
      }
#pragma unroll
      for (int m = 0; m < 4; ++m)
#pragma unroll
        for (int n = 0; n < 2; ++n)
          acc[m][n] = __builtin_amdgcn_mfma_f32_16x16x32_bf16(
              af[m], bfr[n], acc[m][n], 0, 0, 0);
    }
  }

#pragma unroll
  for (int m = 0; m < 4; ++m)
#pragma unroll
    for (int n = 0; n < 2; ++n) {
      const int row0 = bm * 128 + wr * 64 + m * 16 + (l >> 4) * 4;
      const int col = bn * 64 + wc * 32 + n * 16 + (l & 15);
#pragma unroll
      for (int r = 0; r < 4; ++r)
        C[(size_t)(row0 + r) * NROWS + col] = acc[m][n][r];
    }
}

// -------------------------------------------------- per-row sampling + CE loss
__global__ __launch_bounds__(1024) void sample_loss(
    const float* __restrict__ f, const float* __restrict__ f_nv,
    const float* __restrict__ features, const int* __restrict__ labels,
    const int* __restrict__ indexes, const float* __restrict__ mat_sim,
    float* __restrict__ row_loss,
    uint32_t k1a, uint32_t k1b, uint32_t k2a, uint32_t k2b,
    uint32_t k3a, uint32_t k3b) {
  __shared__ uint32_t keys[NROWS];      // 128 KiB sortable uniform bits
  __shared__ uint32_t hist4[4][256];    // privatized histograms
  __shared__ uint32_t hist[256];
  __shared__ unsigned long long am1, am2;
  __shared__ int tie_j[128];
  __shared__ int tie_cnt;
  __shared__ float sred[16];
  __shared__ float swm[16], sws[16];
  __shared__ uint32_t bc_prefix, bc_rem;
  __shared__ int blab_s;

  const int t = threadIdx.x;
  const int i = blockIdx.x;
  const size_t mbase = (size_t)i * NROWS;

  if (t == 0) {
    blab_s = labels[indexes[i]];
    am1 = 0ull; am2 = 0ull; tie_cnt = 0;
  }
  ((uint32_t*)hist4)[t] = 0u;           // pass-0 histogram built during phase 1
  __syncthreads();
  const int blab = blab_s;
  const int hsel = t >> 8;

#pragma unroll 2
  for (int s = 0; s < NROWS / 1024; ++s) {
    int j = t + 1024 * s;
    uint32_t q = (uint32_t)i * NROWS + (uint32_t)j;
    int lab = labels[j];
    uint32_t key;
    if (lab == blab) {
      key = 0u;
      unsigned long long lo = (unsigned long long)(uint32_t)(NROWS - 1 - j);
      uint32_t u1 = ubits_at(k1a, k1b, q);
      uint32_t u2 = ubits_at(k2a, k2b, q);
      atomicMax(&am1, ((unsigned long long)u1 << 32) | lo);
      atomicMax(&am2, ((unsigned long long)u2 << 32) | lo);
    } else {
      key = ubits_at(k3a, k3b, q);
    }
    keys[j] = key;
    atomicAdd(&hist4[hsel][key >> 15], 1u);
  }
  __syncthreads();

  const int jw = NROWS - 1 - (int)(unsigned)(am1 & 0xFFFFFFFFull);
  const int jp = NROWS - 1 - (int)(unsigned)(am2 & 0xFFFFFFFFull);

  const int bank = indexes[i];
  float d1 = 0.f, d2 = 0.f, d3 = 0.f;
  for (int d = t; d < DIM; d += 1024) {
    float fnv = f_nv[(size_t)i * DIM + d];
    d1 += fnv * features[(size_t)bank * DIM + d];
    d2 += f[(size_t)i * DIM + d] * features[(size_t)jw * DIM + d];
    d3 += fnv * features[(size_t)jp * DIM + d];
  }
  const float l_pos = block_sum(d1, sred);
  const float posw  = block_sum(d2, sred);
  const float posv  = block_sum(d3, sred);

  uint32_t prefix = 0, remaining = KNEG;
  const int shifts[3] = {15, 7, 0};
  const int nbits[3]  = {8, 8, 7};
  for (int p = 0; p < 3; ++p) {
    const int sh = shifts[p];
    const int nb = 1 << nbits[p];
    if (p) {
      ((uint32_t*)hist4)[t] = 0u;
      __syncthreads();
      for (int s = 0; s < NROWS / 1024; ++s) {
        int j = t + 1024 * s;
        uint32_t k = keys[j];
        if ((k >> (sh + nbits[p])) == prefix)
          atomicAdd(&hist4[hsel][(k >> sh) & (uint32_t)(nb - 1)], 1u);
      }
    }
    __syncthreads();
    if (t < nb) hist[t] = hist4[0][t] + hist4[1][t] + hist4[2][t] + hist4[3][t];
    __syncthreads();
    if (t == 0) {
      uint32_t c = 0; int b = nb - 1;
      for (;; --b) {
        c += hist[b];
        if (c >= remaining || b == 0) break;
      }
      bc_prefix = (prefix << nbits[p]) | (uint32_t)b;
      bc_rem = remaining - (c - hist[b]);
    }
    __syncthreads();
    prefix = bc_prefix; remaining = bc_rem;
  }
  const uint32_t T = prefix;
  const uint32_t need = remaining;

  float m = -INFINITY, ssum = 0.f;
  for (int s = 0; s < NROWS / 1024; ++s) {
    int j = t + 1024 * s;
    uint32_t k = keys[j];
    if (k > T) {
      float v = mat_sim[mbase + j] / TEMP;
      if (v <= m) ssum += expf(v - m);
      else { ssum = ssum * expf(m - v) + 1.0f; m = v; }
    } else if (k == T) {
      int p = atomicAdd(&tie_cnt, 1);
      if (p < 128) tie_j[p] = j;
    }
  }
  for (int o = 32; o; o >>= 1) {
    float m2 = __shfl_down(m, o, 64);
    float s2 = __shfl_down(ssum, o, 64);
    if (m2 > m) { ssum = ssum * expf(m - m2) + s2; m = m2; }
    else if (m2 != -INFINITY) ssum += s2 * expf(m2 - m);
  }
  if ((t & 63) == 0) { swm[t >> 6] = m; sws[t >> 6] = ssum; }
  __syncthreads();
  if (t < 64) {
    float mm = (t < 16) ? swm[t] : -INFINITY;
    float ss = (t < 16) ? sws[t] : 0.f;
    for (int o = 8; o; o >>= 1) {
      float m2 = __shfl_down(mm, o, 64);
      float s2 = __shfl_down(ss, o, 64);
      if (m2 > mm) { ss = ss * expf(mm - m2) + s2; mm = m2; }
      else if (m2 != -INFINITY) ss += s2 * expf(m2 - mm);
    }
    if (t == 0) { swm[0] = mm; sws[0] = ss; }
  }
  __syncthreads();

  if (t == 0) {
    float M = swm[0], S = sws[0];
    int tc = tie_cnt;
    if (tc <= 128) {
      for (int a2 = 1; a2 < tc; ++a2) {
        int v = tie_j[a2]; int b2 = a2 - 1;
        while (b2 >= 0 && tie_j[b2] > v) { tie_j[b2 + 1] = tie_j[b2]; --b2; }
        tie_j[b2 + 1] = v;
      }
      for (uint32_t r = 0; r < need; ++r) {
        float v = mat_sim[mbase + tie_j[r]] / TEMP;
        if (v <= M) S += expf(v - M);
        else { S = S * expf(M - v) + 1.0f; M = v; }
      }
    } else {
      uint32_t taken = 0;
      for (int j = 0; j < NROWS && taken < need; ++j) {
        if (keys[j] == T) {
          float v = mat_sim[mbase + j] / TEMP;
          if (v <= M) S += expf(v - M);
          else { S = S * expf(M - v) + 1.0f; M = v; }
          ++taken;
        }
      }
    }
    float lp = l_pos / TEMP, pv = posv / TEMP, pw = posw / TEMP;
    float L = 0.f;
    { float X = fmaxf(M, lp); L += X + logf(expf(lp - X) + S * expf(M - X)) - lp; }
    { float X = fmaxf(M, pv); L += X + logf(expf(pv - X) + S * expf(M - X)) - pv; }
    { float X = fmaxf(M, pw); L += X + logf(expf(pw - X) + S * expf(M - X)) - pw; }
    row_loss[i] = L;
  }
}

// ---------------------------------------------------------------- finalize loss
__global__ void finalize_loss(const float* __restrict__ row_loss,
                              float* __restrict__ out) {
  __shared__ float sm[4];
  int t = threadIdx.x;
  float v = row_loss[t];
  for (int o = 32; o; o >>= 1) v += __shfl_down(v, o, 64);
  if ((t & 63) == 0) sm[t >> 6] = v;
  __syncthreads();
  if (t == 0) out[0] = (sm[0] + sm[1] + sm[2] + sm[3]) * (1.0f / BATCH);
}

// -------------------------------- fallback cleanup: copy front rows afterwards
__global__ void copy_front(const float* __restrict__ src,
                           float* __restrict__ dst, int n4) {
  int idx = blockIdx.x * blockDim.x + threadIdx.x;
  int stride = gridDim.x * blockDim.x;
  for (int i = idx; i < n4; i += stride) {
    f32x4 v = *(const f32x4*)&src[(size_t)i * 4];
    float* d = &dst[(size_t)i * 4];
    d[0] = v[0]; d[1] = v[1]; d[2] = v[2]; d[3] = v[3];
  }
}

// --------------------------------------------- momentum update of touched rows
__global__ __launch_bounds__(256) void update_rows(
    const float* __restrict__ f, const float* __restrict__ features,
    const int* __restrict__ indexes, float* __restrict__ outF) {
  __shared__ float sred[16];
  const int i = blockIdx.x;
  const int row = indexes[i];
  for (int i2 = i + 1; i2 < BATCH; ++i2)
    if (indexes[i2] == row) return;          // last occurrence wins
  const int t = threadIdx.x;
  float ss = 0.f;
  for (int d = t; d < DIM; d += 256) {
    float u = 0.2f * features[(size_t)row * DIM + d] + 0.8f * f[(size_t)i * DIM + d];
    ss += u * u;
  }
  ss = block_sum(ss, sred);
  float nrm = fmaxf(sqrtf(ss), 1e-12f);
  for (int d = t; d < DIM; d += 256) {
    float u = 0.2f * features[(size_t)row * DIM + d] + 0.8f * f[(size_t)i * DIM + d];
    outF[(size_t)row * DIM + d] = u / nrm;
  }
}

// ------------------------------------------------------------------- launcher
extern "C" void kernel_launch(void* const* d_in, const int* in_sizes, int n_in,
                              void* d_out, int out_size, void* d_ws, size_t ws_size,
                              hipStream_t stream) {
  (void)in_sizes; (void)n_in; (void)out_size;
  const float* f        = (const float*)d_in[0];
  const float* f_nv     = (const float*)d_in[1];
  const float* features = (const float*)d_in[2];
  const int*   labels   = (const int*)d_in[3];
  const int*   indexes  = (const int*)d_in[4];
  float* out = (float*)d_out;

  // scratch: mat_sim 32MB + row_loss + Abf 1MB + fbf16 64MB; prefer d_ws
  const size_t n_mat = (size_t)BATCH * NROWS;           // 8,388,608 floats
  const size_t n_scratch = n_mat + 256 + 262144 + (size_t)NROWS * DIM / 2;
  float* mat_sim;
  float* row_loss;
  uint32_t* Abf;
  uint32_t* fbf16;
  int skip_rows;
  bool use_ws = (d_ws != nullptr) && (ws_size >= n_scratch * sizeof(float));
  if (use_ws) {
    mat_sim = (float*)d_ws;
    skip_rows = 0;
  } else {
    mat_sim = out + 4;
    skip_rows = 12544;  // scratch occupies outF rows < 12544; fixed by copy_front
  }
  row_loss = mat_sim + n_mat;
  Abf = (uint32_t*)(row_loss + 256);
  fbf16 = Abf + 262144;

  // kg1..kg3 = split(key(42), 3), partitionable threefry
  uint32_t c[6];
  { uint32_t a, b;
    tf2x32(0u, 42u, 0u, 0u, a, b); c[0] = a; c[1] = b;
    tf2x32(0u, 42u, 0u, 1u, a, b); c[2] = a; c[3] = b;
    tf2x32(0u, 42u, 0u, 2u, a, b); c[4] = a; c[5] = b; }

  cvtA<<<dim3(256), dim3(256), 0, stream>>>(f_nv, Abf);
  prep<<<dim3(2048), dim3(256), 0, stream>>>(features, out + 1, fbf16, skip_rows);
  gemm_bf<<<dim3(2 * NROWS / 64), dim3(256), 0, stream>>>(Abf, fbf16, mat_sim);
  sample_loss<<<dim3(BATCH), dim3(1024), 0, stream>>>(
      f, f_nv, features, labels, indexes, mat_sim, row_loss,
      c[0], c[1], c[2], c[3], c[4], c[5]);
  finalize_loss<<<dim3(1), dim3(256), 0, stream>>>(row_loss, out);
  if (!use_ws) {
    copy_front<<<dim3(2048), dim3(256), 0, stream>>>(
        features, out + 1, 12544 * DIM / 4);
  }
  update_rows<<<dim3(BATCH), dim3(256), 0, stream>>>(f, features, indexes, out + 1);
}

// Round 11
// 340.591 us; speedup vs baseline: 1.0391x; 1.0391x over previous
//
#include <hip/hip_runtime.h>
#include <stdint.h>

#define TEMP      0.07f
#define BATCH     256
#define NROWS     32768
#define DIM       2048
#define KNEG      8192

typedef __attribute__((ext_vector_type(8))) short bf16x8;
typedef __attribute__((ext_vector_type(4))) float f32x4;

// ---------------------------------------------------------------- threefry2x32
__host__ __device__ inline void tf2x32(uint32_t ka, uint32_t kb,
                                       uint32_t x0, uint32_t x1,
                                       uint32_t& o0, uint32_t& o1) {
  uint32_t ks2 = ka ^ kb ^ 0x1BD11BDAu;
#define TFR(r) { x0 += x1; x1 = (x1 << r) | (x1 >> (32 - r)); x1 ^= x0; }
  x0 += ka; x1 += kb;
  TFR(13) TFR(15) TFR(26) TFR(6)
  x0 += kb;  x1 += ks2 + 1u;
  TFR(17) TFR(29) TFR(16) TFR(24)
  x0 += ks2; x1 += ka + 2u;
  TFR(13) TFR(15) TFR(26) TFR(6)
  x0 += ka;  x1 += kb + 3u;
  TFR(17) TFR(29) TFR(16) TFR(24)
  x0 += kb;  x1 += ks2 + 4u;
  TFR(13) TFR(15) TFR(26) TFR(6)
  x0 += ks2; x1 += ka + 5u;
#undef TFR
  o0 = x0; o1 = x1;
}

// partitionable threefry (JAX >= 0.4.36): bits = out0 ^ out1, counter = (0, q)
__device__ inline uint32_t ubits_at(uint32_t ka, uint32_t kb, uint32_t q) {
  uint32_t a, b; tf2x32(ka, kb, 0u, q, a, b);
  return (a ^ b) >> 9;
}

// ---------------------------------------------------------------- block reduce
__device__ inline float block_sum(float v, float* sm) {
  __syncthreads();
  const int lane = threadIdx.x & 63;
  const int w = threadIdx.x >> 6;
  const int nw = blockDim.x >> 6;
  for (int o = 32; o; o >>= 1) v += __shfl_down(v, o, 64);
  if (lane == 0) sm[w] = v;
  __syncthreads();
  if (w == 0) {
    float x = (lane < nw) ? sm[lane] : 0.f;
    for (int o = 8; o; o >>= 1) x += __shfl_down(x, o, 64);
    if (lane == 0) sm[0] = x;
  }
  __syncthreads();
  return sm[0];
}

__device__ inline uint32_t pk2(float a, float b) {  // 2x fp32 -> packed bf16 (RNE)
  uint32_t ua = __float_as_uint(a), ub = __float_as_uint(b);
  ua = (ua + 0x7FFFu + ((ua >> 16) & 1u)) >> 16;
  ub = (ub + 0x7FFFu + ((ub >> 16) & 1u)) >> 16;
  return ua | (ub << 16);
}

// -------------------------- pack f_nv into bf16 MFMA A-fragment layout (1 MB)
// Fragment tile (mt,kt): 1 KB, lane l holds rows mt*16+(l&15), k kt*32+(l>>4)*8.
__global__ __launch_bounds__(256) void cvtA(const float* __restrict__ A,
                                            uint32_t* __restrict__ Abf) {
  const int t = threadIdx.x;
  const int w = blockIdx.x * 4 + (t >> 6);   // 1024 fragment tiles
  const int l = t & 63;
  const int mt = w >> 6, kt = w & 63;
  const float* src = &A[(size_t)(mt * 16 + (l & 15)) * DIM + kt * 32 + (l >> 4) * 8];
  float4 f0 = *(const float4*)src;
  float4 f1 = *(const float4*)(src + 4);
  *(uint4*)(Abf + (size_t)w * 256 + l * 4) =
      make_uint4(pk2(f0.x, f0.y), pk2(f0.z, f0.w), pk2(f1.x, f1.y), pk2(f1.z, f1.w));
}

// ---------------- prep: stream features -> outF (fp32) + fbf16 (row-major)
// Round-9 structure verbatim (measured 175 us); single change: outF uses
// REGULAR stores (A/B vs nontemporal — fillBufferAligned hits 6.9 TB/s with
// regular stores while all our nt-store streams plateau at ~3 TB/s).
__global__ __launch_bounds__(256) void prep(const float* __restrict__ src,
                                            float* __restrict__ outF,
                                            uint32_t* __restrict__ fbf16,
                                            int skip) {
  const int stride = gridDim.x * blockDim.x;          // in 16B granules
  const int total = NROWS * DIM / 4;
  for (int i = blockIdx.x * blockDim.x + threadIdx.x; i < total; i += stride) {
    f32x4 v = *(const f32x4*)(src + (size_t)i * 4);
    uint2 b = make_uint2(pk2(v[0], v[1]), pk2(v[2], v[3]));
    *(uint2*)(fbf16 + (size_t)i * 2) = b;
    if ((i >> 9) >= skip)                              // row = i*4/DIM
      *(f32x4*)(outF + (size_t)i * 4) = v;
  }
}

// ------------------------------------------------------- async LDS staging DMA
__device__ inline void gll16(const uint32_t* g, uint32_t* l) {
  __builtin_amdgcn_global_load_lds(
      (const __attribute__((address_space(1))) uint32_t*)g,
      (__attribute__((address_space(3))) uint32_t*)l, 16, 0, 0);
}

// ------------------- m97-shape bf16 GEMM: B from L3-hot fbf16 via gll
// BM=128 x BN=64 x BK=64 bf16 -> 1024 blocks, 4 blocks/CU (8 KiB LDS each).
// Single-buffered 2-barrier loop; cross-block TLP hides the barrier drain.
__global__ __launch_bounds__(256, 4) void gemm_bf(
    const uint32_t* __restrict__ Abf,    // packed f_nv bf16 A-fragments
    const uint32_t* __restrict__ fbf16,  // features bf16 [32768][2048]
    float* __restrict__ C) {             // mat_sim [256][32768]
  __shared__ uint32_t Bs[64 * 32];       // 8 KiB: 64 rows x 128 B
  const int t = threadIdx.x;
  const int l = t & 63, w = t >> 6;
  const int bm = blockIdx.x & 1;
  const int bn = blockIdx.x >> 1;
  const int wr = w >> 1, wc = w & 1;     // 2x2 waves: 64x32 out each

  f32x4 acc[4][2] = {};

  for (int t0 = 0; t0 < DIM / 64; ++t0) {
    __syncthreads();                     // previous tile consumed
#pragma unroll
    for (int i = 0; i < 2; ++i) {
      const int ii = w * 2 + i;                  // 8 x 1KB DMAs
      const int r = ii * 8 + (l >> 3);           // tile row 0..63
      const int g = (l & 7) ^ (r & 7);           // src granule for LDS slot l&7
      gll16(&fbf16[(size_t)(bn * 64 + r) * (DIM / 2) + t0 * 32 + g * 4],
            &Bs[ii * 256]);
    }
    __syncthreads();                     // tile ready (compiler drains vmcnt)
#pragma unroll
    for (int kk = 0; kk < 2; ++kk) {
      bf16x8 af[4];
#pragma unroll
      for (int m = 0; m < 4; ++m)
        af[m] = *(const bf16x8*)(Abf +
            ((size_t)((bm * 8 + wr * 4 + m) * 64 + t0 * 2 + kk) * 64 + l) * 4);
      bf16x8 bfr[2];
#pragma unroll
      for (int n = 0; n < 2; ++n) {
        const int R = wc * 32 + n * 16 + (l & 15);
        const int slot = (kk * 4 + (l >> 4)) ^ (R & 7);
        bfr[n] = *(const bf16x8*)&Bs[R * 32 + slot * 4];
      }
#pragma unroll
      for (int m = 0; m < 4; ++m)
#pragma unroll
        for (int n = 0; n < 2; ++n)
          acc[m][n] = __builtin_amdgcn_mfma_f32_16x16x32_bf16(
              af[m], bfr[n], acc[m][n], 0, 0, 0);
    }
  }

#pragma unroll
  for (int m = 0; m < 4; ++m)
#pragma unroll
    for (int n = 0; n < 2; ++n) {
      const int row0 = bm * 128 + wr * 64 + m * 16 + (l >> 4) * 4;
      const int col = bn * 64 + wc * 32 + n * 16 + (l & 15);
#pragma unroll
      for (int r = 0; r < 4; ++r)
        C[(size_t)(row0 + r) * NROWS + col] = acc[m][n][r];
    }
}

// -------------------------------------------------- per-row sampling + CE loss
__global__ __launch_bounds__(1024) void sample_loss(
    const float* __restrict__ f, const float* __restrict__ f_nv,
    const float* __restrict__ features, const int* __restrict__ labels,
    const int* __restrict__ indexes, const float* __restrict__ mat_sim,
    float* __restrict__ row_loss,
    uint32_t k1a, uint32_t k1b, uint32_t k2a, uint32_t k2b,
    uint32_t k3a, uint32_t k3b) {
  __shared__ uint32_t keys[NROWS];      // 128 KiB sortable uniform bits
  __shared__ uint32_t hist4[4][256];    // privatized histograms
  __shared__ uint32_t hist[256];
  __shared__ unsigned long long am1, am2;
  __shared__ int tie_j[128];
  __shared__ int tie_cnt;
  __shared__ float sred[16];
  __shared__ float swm[16], sws[16];
  __shared__ uint32_t bc_prefix, bc_rem;
  __shared__ int blab_s;

  const int t = threadIdx.x;
  const int i = blockIdx.x;
  const size_t mbase = (size_t)i * NROWS;

  if (t == 0) {
    blab_s = labels[indexes[i]];
    am1 = 0ull; am2 = 0ull; tie_cnt = 0;
  }
  ((uint32_t*)hist4)[t] = 0u;           // pass-0 histogram built during phase 1
  __syncthreads();
  const int blab = blab_s;
  const int hsel = t >> 8;

#pragma unroll 2
  for (int s = 0; s < NROWS / 1024; ++s) {
    int j = t + 1024 * s;
    uint32_t q = (uint32_t)i * NROWS + (uint32_t)j;
    int lab = labels[j];
    uint32_t key;
    if (lab == blab) {
      key = 0u;
      unsigned long long lo = (unsigned long long)(uint32_t)(NROWS - 1 - j);
      uint32_t u1 = ubits_at(k1a, k1b, q);
      uint32_t u2 = ubits_at(k2a, k2b, q);
      atomicMax(&am1, ((unsigned long long)u1 << 32) | lo);
      atomicMax(&am2, ((unsigned long long)u2 << 32) | lo);
    } else {
      key = ubits_at(k3a, k3b, q);
    }
    keys[j] = key;
    atomicAdd(&hist4[hsel][key >> 15], 1u);
  }
  __syncthreads();

  const int jw = NROWS - 1 - (int)(unsigned)(am1 & 0xFFFFFFFFull);
  const int jp = NROWS - 1 - (int)(unsigned)(am2 & 0xFFFFFFFFull);

  const int bank = indexes[i];
  float d1 = 0.f, d2 = 0.f, d3 = 0.f;
  for (int d = t; d < DIM; d += 1024) {
    float fnv = f_nv[(size_t)i * DIM + d];
    d1 += fnv * features[(size_t)bank * DIM + d];
    d2 += f[(size_t)i * DIM + d] * features[(size_t)jw * DIM + d];
    d3 += fnv * features[(size_t)jp * DIM + d];
  }
  const float l_pos = block_sum(d1, sred);
  const float posw  = block_sum(d2, sred);
  const float posv  = block_sum(d3, sred);

  uint32_t prefix = 0, remaining = KNEG;
  const int shifts[3] = {15, 7, 0};
  const int nbits[3]  = {8, 8, 7};
  for (int p = 0; p < 3; ++p) {
    const int sh = shifts[p];
    const int nb = 1 << nbits[p];
    if (p) {
      ((uint32_t*)hist4)[t] = 0u;
      __syncthreads();
      for (int s = 0; s < NROWS / 1024; ++s) {
        int j = t + 1024 * s;
        uint32_t k = keys[j];
        if ((k >> (sh + nbits[p])) == prefix)
          atomicAdd(&hist4[hsel][(k >> sh) & (uint32_t)(nb - 1)], 1u);
      }
    }
    __syncthreads();
    if (t < nb) hist[t] = hist4[0][t] + hist4[1][t] + hist4[2][t] + hist4[3][t];
    __syncthreads();
    if (t == 0) {
      uint32_t c = 0; int b = nb - 1;
      for (;; --b) {
        c += hist[b];
        if (c >= remaining || b == 0) break;
      }
      bc_prefix = (prefix << nbits[p]) | (uint32_t)b;
      bc_rem = remaining - (c - hist[b]);
    }
    __syncthreads();
    prefix = bc_prefix; remaining = bc_rem;
  }
  const uint32_t T = prefix;
  const uint32_t need = remaining;

  float m = -INFINITY, ssum = 0.f;
  for (int s = 0; s < NROWS / 1024; ++s) {
    int j = t + 1024 * s;
    uint32_t k = keys[j];
    if (k > T) {
      float v = mat_sim[mbase + j] / TEMP;
      if (v <= m) ssum += expf(v - m);
      else { ssum = ssum * expf(m - v) + 1.0f; m = v; }
    } else if (k == T) {
      int p = atomicAdd(&tie_cnt, 1);
      if (p < 128) tie_j[p] = j;
    }
  }
  for (int o = 32; o; o >>= 1) {
    float m2 = __shfl_down(m, o, 64);
    float s2 = __shfl_down(ssum, o, 64);
    if (m2 > m) { ssum = ssum * expf(m - m2) + s2; m = m2; }
    else if (m2 != -INFINITY) ssum += s2 * expf(m2 - m);
  }
  if ((t & 63) == 0) { swm[t >> 6] = m; sws[t >> 6] = ssum; }
  __syncthreads();
  if (t < 64) {
    float mm = (t < 16) ? swm[t] : -INFINITY;
    float ss = (t < 16) ? sws[t] : 0.f;
    for (int o = 8; o; o >>= 1) {
      float m2 = __shfl_down(mm, o, 64);
      float s2 = __shfl_down(ss, o, 64);
      if (m2 > mm) { ss = ss * expf(mm - m2) + s2; mm = m2; }
      else if (m2 != -INFINITY) ss += s2 * expf(m2 - mm);
    }
    if (t == 0) { swm[0] = mm; sws[0] = ss; }
  }
  __syncthreads();

  if (t == 0) {
    float M = swm[0], S = sws[0];
    int tc = tie_cnt;
    if (tc <= 128) {
      for (int a2 = 1; a2 < tc; ++a2) {
        int v = tie_j[a2]; int b2 = a2 - 1;
        while (b2 >= 0 && tie_j[b2] > v) { tie_j[b2 + 1] = tie_j[b2]; --b2; }
        tie_j[b2 + 1] = v;
      }
      for (uint32_t r = 0; r < need; ++r) {
        float v = mat_sim[mbase + tie_j[r]] / TEMP;
        if (v <= M) S += expf(v - M);
        else { S = S * expf(M - v) + 1.0f; M = v; }
      }
    } else {
      uint32_t taken = 0;
      for (int j = 0; j < NROWS && taken < need; ++j) {
        if (keys[j] == T) {
          float v = mat_sim[mbase + j] / TEMP;
          if (v <= M) S += expf(v - M);
          else { S = S * expf(M - v) + 1.0f; M = v; }
          ++taken;
        }
      }
    }
    float lp = l_pos / TEMP, pv = posv / TEMP, pw = posw / TEMP;
    float L = 0.f;
    { float X = fmaxf(M, lp); L += X + logf(expf(lp - X) + S * expf(M - X)) - lp; }
    { float X = fmaxf(M, pv); L += X + logf(expf(pv - X) + S * expf(M - X)) - pv; }
    { float X = fmaxf(M, pw); L += X + logf(expf(pw - X) + S * expf(M - X)) - pw; }
    row_loss[i] = L;
  }
}

// ---------------------------------------------------------------- finalize loss
__global__ void finalize_loss(const float* __restrict__ row_loss,
                              float* __restrict__ out) {
  __shared__ float sm[4];
  int t = threadIdx.x;
  float v = row_loss[t];
  for (int o = 32; o; o >>= 1) v += __shfl_down(v, o, 64);
  if ((t & 63) == 0) sm[t >> 6] = v;
  __syncthreads();
  if (t == 0) out[0] = (sm[0] + sm[1] + sm[2] + sm[3]) * (1.0f / BATCH);
}

// -------------------------------- fallback cleanup: copy front rows afterwards
__global__ void copy_front(const float* __restrict__ src,
                           float* __restrict__ dst, int n4) {
  int idx = blockIdx.x * blockDim.x + threadIdx.x;
  int stride = gridDim.x * blockDim.x;
  for (int i = idx; i < n4; i += stride) {
    f32x4 v = *(const f32x4*)&src[(size_t)i * 4];
    float* d = &dst[(size_t)i * 4];
    d[0] = v[0]; d[1] = v[1]; d[2] = v[2]; d[3] = v[3];
  }
}

// --------------------------------------------- momentum update of touched rows
__global__ __launch_bounds__(256) void update_rows(
    const float* __restrict__ f, const float* __restrict__ features,
    const int* __restrict__ indexes, float* __restrict__ outF) {
  __shared__ float sred[16];
  const int i = blockIdx.x;
  const int row = indexes[i];
  for (int i2 = i + 1; i2 < BATCH; ++i2)
    if (indexes[i2] == row) return;          // last occurrence wins
  const int t = threadIdx.x;
  float ss = 0.f;
  for (int d = t; d < DIM; d += 256) {
    float u = 0.2f * features[(size_t)row * DIM + d] + 0.8f * f[(size_t)i * DIM + d];
    ss += u * u;
  }
  ss = block_sum(ss, sred);
  float nrm = fmaxf(sqrtf(ss), 1e-12f);
  for (int d = t; d < DIM; d += 256) {
    float u = 0.2f * features[(size_t)row * DIM + d] + 0.8f * f[(size_t)i * DIM + d];
    outF[(size_t)row * DIM + d] = u / nrm;
  }
}

// ------------------------------------------------------------------- launcher
extern "C" void kernel_launch(void* const* d_in, const int* in_sizes, int n_in,
                              void* d_out, int out_size, void* d_ws, size_t ws_size,
                              hipStream_t stream) {
  (void)in_sizes; (void)n_in; (void)out_size;
  const float* f        = (const float*)d_in[0];
  const float* f_nv     = (const float*)d_in[1];
  const float* features = (const float*)d_in[2];
  const int*   labels   = (const int*)d_in[3];
  const int*   indexes  = (const int*)d_in[4];
  float* out = (float*)d_out;

  // scratch: mat_sim 32MB + row_loss + Abf 1MB + fbf16 64MB; prefer d_ws
  const size_t n_mat = (size_t)BATCH * NROWS;           // 8,388,608 floats
  const size_t n_scratch = n_mat + 256 + 262144 + (size_t)NROWS * DIM / 2;
  float* mat_sim;
  float* row_loss;
  uint32_t* Abf;
  uint32_t* fbf16;
  int skip_rows;
  bool use_ws = (d_ws != nullptr) && (ws_size >= n_scratch * sizeof(float));
  if (use_ws) {
    mat_sim = (float*)d_ws;
    skip_rows = 0;
  } else {
    mat_sim = out + 4;
    skip_rows = 12544;  // scratch occupies outF rows < 12544; fixed by copy_front
  }
  row_loss = mat_sim + n_mat;
  Abf = (uint32_t*)(row_loss + 256);
  fbf16 = Abf + 262144;

  // kg1..kg3 = split(key(42), 3), partitionable threefry
  uint32_t c[6];
  { uint32_t a, b;
    tf2x32(0u, 42u, 0u, 0u, a, b); c[0] = a; c[1] = b;
    tf2x32(0u, 42u, 0u, 1u, a, b); c[2] = a; c[3] = b;
    tf2x32(0u, 42u, 0u, 2u, a, b); c[4] = a; c[5] = b; }

  cvtA<<<dim3(256), dim3(256), 0, stream>>>(f_nv, Abf);
  prep<<<dim3(2048), dim3(256), 0, stream>>>(features, out + 1, fbf16, skip_rows);
  gemm_bf<<<dim3(2 * NROWS / 64), dim3(256), 0, stream>>>(Abf, fbf16, mat_sim);
  sample_loss<<<dim3(BATCH), dim3(1024), 0, stream>>>(
      f, f_nv, features, labels, indexes, mat_sim, row_loss,
      c[0], c[1], c[2], c[3], c[4], c[5]);
  finalize_loss<<<dim3(1), dim3(256), 0, stream>>>(row_loss, out);
  if (!use_ws) {
    copy_front<<<dim3(2048), dim3(256), 0, stream>>>(
        features, out + 1, 12544 * DIM / 4);
  }
  update_rows<<<dim3(BATCH), dim3(256), 0, stream>>>(f, features, indexes, out + 1);
}

// Round 12
// 337.630 us; speedup vs baseline: 1.0482x; 1.0088x over previous
//
#include <hip/hip_runtime.h>
#include <stdint.h>

#define TEMP      0.07f
#define BATCH     256
#define NROWS     32768
#define DIM       2048
#define KNEG      8192

typedef __attribute__((ext_vector_type(8))) short bf16x8;
typedef __attribute__((ext_vector_type(4))) float f32x4;

// ---------------------------------------------------------------- threefry2x32
__host__ __device__ inline void tf2x32(uint32_t ka, uint32_t kb,
                                       uint32_t x0, uint32_t x1,
                                       uint32_t& o0, uint32_t& o1) {
  uint32_t ks2 = ka ^ kb ^ 0x1BD11BDAu;
#define TFR(r) { x0 += x1; x1 = (x1 << r) | (x1 >> (32 - r)); x1 ^= x0; }
  x0 += ka; x1 += kb;
  TFR(13) TFR(15) TFR(26) TFR(6)
  x0 += kb;  x1 += ks2 + 1u;
  TFR(17) TFR(29) TFR(16) TFR(24)
  x0 += ks2; x1 += ka + 2u;
  TFR(13) TFR(15) TFR(26) TFR(6)
  x0 += ka;  x1 += kb + 3u;
  TFR(17) TFR(29) TFR(16) TFR(24)
  x0 += kb;  x1 += ks2 + 4u;
  TFR(13) TFR(15) TFR(26) TFR(6)
  x0 += ks2; x1 += ka + 5u;
#undef TFR
  o0 = x0; o1 = x1;
}

// partitionable threefry (JAX >= 0.4.36): bits = out0 ^ out1, counter = (0, q)
__device__ inline uint32_t ubits_at(uint32_t ka, uint32_t kb, uint32_t q) {
  uint32_t a, b; tf2x32(ka, kb, 0u, q, a, b);
  return (a ^ b) >> 9;
}

// ---------------------------------------------------------------- block reduce
__device__ inline float block_sum(float v, float* sm) {
  __syncthreads();
  const int lane = threadIdx.x & 63;
  const int w = threadIdx.x >> 6;
  const int nw = blockDim.x >> 6;
  for (int o = 32; o; o >>= 1) v += __shfl_down(v, o, 64);
  if (lane == 0) sm[w] = v;
  __syncthreads();
  if (w == 0) {
    float x = (lane < nw) ? sm[lane] : 0.f;
    for (int o = 8; o; o >>= 1) x += __shfl_down(x, o, 64);
    if (lane == 0) sm[0] = x;
  }
  __syncthreads();
  return sm[0];
}

__device__ inline uint32_t pk2(float a, float b) {  // 2x fp32 -> packed bf16 (RNE)
  uint32_t ua = __float_as_uint(a), ub = __float_as_uint(b);
  ua = (ua + 0x7FFFu + ((ua >> 16) & 1u)) >> 16;
  ub = (ub + 0x7FFFu + ((ub >> 16) & 1u)) >> 16;
  return ua | (ub << 16);
}

// -------------------------- pack f_nv into bf16 MFMA A-fragment layout (1 MB)
// Fragment tile (mt,kt): 1 KB, lane l holds rows mt*16+(l&15), k kt*32+(l>>4)*8.
__global__ __launch_bounds__(256) void cvtA(const float* __restrict__ A,
                                            uint32_t* __restrict__ Abf) {
  const int t = threadIdx.x;
  const int w = blockIdx.x * 4 + (t >> 6);   // 1024 fragment tiles
  const int l = t & 63;
  const int mt = w >> 6, kt = w & 63;
  const float* src = &A[(size_t)(mt * 16 + (l & 15)) * DIM + kt * 32 + (l >> 4) * 8];
  float4 f0 = *(const float4*)src;
  float4 f1 = *(const float4*)(src + 4);
  *(uint4*)(Abf + (size_t)w * 256 + l * 4) =
      make_uint4(pk2(f0.x, f0.y), pk2(f0.z, f0.w), pk2(f1.x, f1.y), pk2(f1.z, f1.w));
}

// ---------------- prep: stream features -> outF (fp32) + fbf16 (row-major)
// 32B per thread-iteration: two ADJACENT f32x4 loads (independent, 2 in
// flight) and all-16B store streams (outF 2x f32x4, fbf16 1x uint4).
__global__ __launch_bounds__(256) void prep(const float* __restrict__ src,
                                            float* __restrict__ outF,
                                            uint32_t* __restrict__ fbf16,
                                            int skip) {
  const int stride = gridDim.x * blockDim.x;
  const int total = NROWS * DIM / 8;            // 32B granules
  const f32x4* __restrict__ s4 = (const f32x4*)src;
  for (int i = blockIdx.x * blockDim.x + threadIdx.x; i < total; i += stride) {
    f32x4 v0 = s4[(size_t)2 * i];
    f32x4 v1 = s4[(size_t)2 * i + 1];
    uint4 b = make_uint4(pk2(v0[0], v0[1]), pk2(v0[2], v0[3]),
                         pk2(v1[0], v1[1]), pk2(v1[2], v1[3]));
    *(uint4*)(fbf16 + (size_t)i * 4) = b;
    if ((i >> 8) >= skip) {                     // row = i*8/DIM
      *(f32x4*)(outF + (size_t)i * 8) = v0;
      *(f32x4*)(outF + (size_t)i * 8 + 4) = v1;
    }
  }
}

// ------------------------------------------------------- async LDS staging DMA
__device__ inline void gll16(const uint32_t* g, uint32_t* l) {
  __builtin_amdgcn_global_load_lds(
      (const __attribute__((address_space(1))) uint32_t*)g,
      (__attribute__((address_space(3))) uint32_t*)l, 16, 0, 0);
}

// ------------------- m97-shape bf16 GEMM (r9 config): B from L3-hot fbf16
// BM=128 x BN=128 x BK=64 bf16, 4 waves (2x2 of 64x64), 512 blocks.
// B-tile 16 KB: 128 rows x 128 B; 4 DMAs/wave, granule-XOR source pre-swizzle.
__global__ __launch_bounds__(256, 3) void gemm_bf(
    const uint32_t* __restrict__ Abf,    // packed f_nv bf16 A-fragments
    const uint32_t* __restrict__ fbf16,  // features bf16 [32768][2048]
    float* __restrict__ C) {             // mat_sim [256][32768]
  __shared__ uint32_t Bs[128 * 32];      // 16 KiB
  const int t = threadIdx.x;
  const int l = t & 63, w = t >> 6;
  const int bm = blockIdx.x & 1;
  const int bn = blockIdx.x >> 1;
  const int wr = w >> 1, wc = w & 1;

  f32x4 acc[4][4] = {};

  for (int t0 = 0; t0 < DIM / 64; ++t0) {
    __syncthreads();                     // previous tile consumed
#pragma unroll
    for (int i = 0; i < 4; ++i) {
      const int r = (w * 4 + i) * 8 + (l >> 3);   // tile row 0..127
      const int g = (l & 7) ^ (r & 7);            // src granule for LDS slot l&7
      gll16(&fbf16[(size_t)(bn * 128 + r) * (DIM / 2) + t0 * 32 + g * 4],
            &Bs[(w * 4 + i) * 256]);
    }
    __syncthreads();                     // tile ready (compiler drains vmcnt)
#pragma unroll
    for (int kk = 0; kk < 2; ++kk) {
      bf16x8 af[4];
#pragma unroll
      for (int m = 0; m < 4; ++m)
        af[m] = *(const bf16x8*)(Abf +
            ((size_t)((bm * 8 + wr * 4 + m) * 64 + t0 * 2 + kk) * 64 + l) * 4);
      bf16x8 bfr[4];
#pragma unroll
      for (int n = 0; n < 4; ++n) {
        const int R = wc * 64 + n * 16 + (l & 15);
        const int slot = (kk * 4 + (l >> 4)) ^ (R & 7);
        bfr[n] = *(const bf16x8*)&Bs[R * 32 + slot * 4];
      }
#pragma unroll
      for (int m = 0; m < 4; ++m)
#pragma unroll
        for (int n = 0; n < 4; ++n)
          acc[m][n] = __builtin_amdgcn_mfma_f32_16x16x32_bf16(
              af[m], bfr[n], acc[m][n], 0, 0, 0);
    }
  }

#pragma unroll
  for (int m = 0; m < 4; ++m)
#pragma unroll
    for (int n = 0; n < 4; ++n) {
      const int row0 = bm * 128 + wr * 64 + m * 16 + (l >> 4) * 4;
      const int col = bn * 128 + wc * 64 + n * 16 + (l & 15);
#pragma unroll
      for (int r = 0; r < 4; ++r)
        C[(size_t)(row0 + r) * NROWS + col] = acc[m][n][r];
    }
}

// -------------------------------------------------- per-row sampling + CE loss
__global__ __launch_bounds__(1024) void sample_loss(
    const float* __restrict__ f, const float* __restrict__ f_nv,
    const float* __restrict__ features, const int* __restrict__ labels,
    const int* __restrict__ indexes, const float* __restrict__ mat_sim,
    float* __restrict__ row_loss,
    uint32_t k1a, uint32_t k1b, uint32_t k2a, uint32_t k2b,
    uint32_t k3a, uint32_t k3b) {
  __shared__ uint32_t keys[NROWS];      // 128 KiB sortable uniform bits
  __shared__ uint32_t hist4[4][256];    // privatized histograms
  __shared__ uint32_t hist[256];
  __shared__ unsigned long long am1, am2;
  __shared__ int tie_j[128];
  __shared__ int tie_cnt;
  __shared__ float sred[16];
  __shared__ float swm[16], sws[16];
  __shared__ uint32_t bc_prefix, bc_rem;
  __shared__ int blab_s;

  const int t = threadIdx.x;
  const int i = blockIdx.x;
  const size_t mbase = (size_t)i * NROWS;

  if (t == 0) {
    blab_s = labels[indexes[i]];
    am1 = 0ull; am2 = 0ull; tie_cnt = 0;
  }
  ((uint32_t*)hist4)[t] = 0u;           // pass-0 histogram built during phase 1
  __syncthreads();
  const int blab = blab_s;
  const int hsel = t >> 8;

#pragma unroll 2
  for (int s = 0; s < NROWS / 1024; ++s) {
    int j = t + 1024 * s;
    uint32_t q = (uint32_t)i * NROWS + (uint32_t)j;
    int lab = labels[j];
    uint32_t key;
    if (lab == blab) {
      key = 0u;
      unsigned long long lo = (unsigned long long)(uint32_t)(NROWS - 1 - j);
      uint32_t u1 = ubits_at(k1a, k1b, q);
      uint32_t u2 = ubits_at(k2a, k2b, q);
      atomicMax(&am1, ((unsigned long long)u1 << 32) | lo);
      atomicMax(&am2, ((unsigned long long)u2 << 32) | lo);
    } else {
      key = ubits_at(k3a, k3b, q);
    }
    keys[j] = key;
    atomicAdd(&hist4[hsel][key >> 15], 1u);
  }
  __syncthreads();

  const int jw = NROWS - 1 - (int)(unsigned)(am1 & 0xFFFFFFFFull);
  const int jp = NROWS - 1 - (int)(unsigned)(am2 & 0xFFFFFFFFull);

  const int bank = indexes[i];
  float d1 = 0.f, d2 = 0.f, d3 = 0.f;
  for (int d = t; d < DIM; d += 1024) {
    float fnv = f_nv[(size_t)i * DIM + d];
    d1 += fnv * features[(size_t)bank * DIM + d];
    d2 += f[(size_t)i * DIM + d] * features[(size_t)jw * DIM + d];
    d3 += fnv * features[(size_t)jp * DIM + d];
  }
  const float l_pos = block_sum(d1, sred);
  const float posw  = block_sum(d2, sred);
  const float posv  = block_sum(d3, sred);

  uint32_t prefix = 0, remaining = KNEG;
  const int shifts[3] = {15, 7, 0};
  const int nbits[3]  = {8, 8, 7};
  for (int p = 0; p < 3; ++p) {
    const int sh = shifts[p];
    const int nb = 1 << nbits[p];
    if (p) {
      ((uint32_t*)hist4)[t] = 0u;
      __syncthreads();
      for (int s = 0; s < NROWS / 1024; ++s) {
        int j = t + 1024 * s;
        uint32_t k = keys[j];
        if ((k >> (sh + nbits[p])) == prefix)
          atomicAdd(&hist4[hsel][(k >> sh) & (uint32_t)(nb - 1)], 1u);
      }
    }
    __syncthreads();
    if (t < nb) hist[t] = hist4[0][t] + hist4[1][t] + hist4[2][t] + hist4[3][t];
    __syncthreads();
    if (t == 0) {
      uint32_t c = 0; int b = nb - 1;
      for (;; --b) {
        c += hist[b];
        if (c >= remaining || b == 0) break;
      }
      bc_prefix = (prefix << nbits[p]) | (uint32_t)b;
      bc_rem = remaining - (c - hist[b]);
    }
    __syncthreads();
    prefix = bc_prefix; remaining = bc_rem;
  }
  const uint32_t T = prefix;
  const uint32_t need = remaining;

  float m = -INFINITY, ssum = 0.f;
  for (int s = 0; s < NROWS / 1024; ++s) {
    int j = t + 1024 * s;
    uint32_t k = keys[j];
    if (k > T) {
      float v = mat_sim[mbase + j] / TEMP;
      if (v <= m) ssum += expf(v - m);
      else { ssum = ssum * expf(m - v) + 1.0f; m = v; }
    } else if (k == T) {
      int p = atomicAdd(&tie_cnt, 1);
      if (p < 128) tie_j[p] = j;
    }
  }
  for (int o = 32; o; o >>= 1) {
    float m2 = __shfl_down(m, o, 64);
    float s2 = __shfl_down(ssum, o, 64);
    if (m2 > m) { ssum = ssum * expf(m - m2) + s2; m = m2; }
    else if (m2 != -INFINITY) ssum += s2 * expf(m2 - m);
  }
  if ((t & 63) == 0) { swm[t >> 6] = m; sws[t >> 6] = ssum; }
  __syncthreads();
  if (t < 64) {
    float mm = (t < 16) ? swm[t] : -INFINITY;
    float ss = (t < 16) ? sws[t] : 0.f;
    for (int o = 8; o; o >>= 1) {
      float m2 = __shfl_down(mm, o, 64);
      float s2 = __shfl_down(ss, o, 64);
      if (m2 > mm) { ss = ss * expf(mm - m2) + s2; mm = m2; }
      else if (m2 != -INFINITY) ss += s2 * expf(m2 - mm);
    }
    if (t == 0) { swm[0] = mm; sws[0] = ss; }
  }
  __syncthreads();

  if (t == 0) {
    float M = swm[0], S = sws[0];
    int tc = tie_cnt;
    if (tc <= 128) {
      for (int a2 = 1; a2 < tc; ++a2) {
        int v = tie_j[a2]; int b2 = a2 - 1;
        while (b2 >= 0 && tie_j[b2] > v) { tie_j[b2 + 1] = tie_j[b2]; --b2; }
        tie_j[b2 + 1] = v;
      }
      for (uint32_t r = 0; r < need; ++r) {
        float v = mat_sim[mbase + tie_j[r]] / TEMP;
        if (v <= M) S += expf(v - M);
        else { S = S * expf(M - v) + 1.0f; M = v; }
      }
    } else {
      uint32_t taken = 0;
      for (int j = 0; j < NROWS && taken < need; ++j) {
        if (keys[j] == T) {
          float v = mat_sim[mbase + j] / TEMP;
          if (v <= M) S += expf(v - M);
          else { S = S * expf(M - v) + 1.0f; M = v; }
          ++taken;
        }
      }
    }
    float lp = l_pos / TEMP, pv = posv / TEMP, pw = posw / TEMP;
    float L = 0.f;
    { float X = fmaxf(M, lp); L += X + logf(expf(lp - X) + S * expf(M - X)) - lp; }
    { float X = fmaxf(M, pv); L += X + logf(expf(pv - X) + S * expf(M - X)) - pv; }
    { float X = fmaxf(M, pw); L += X + logf(expf(pw - X) + S * expf(M - X)) - pw; }
    row_loss[i] = L;
  }
}

// ---------------------------------------------------------------- finalize loss
__global__ void finalize_loss(const float* __restrict__ row_loss,
                              float* __restrict__ out) {
  __shared__ float sm[4];
  int t = threadIdx.x;
  float v = row_loss[t];
  for (int o = 32; o; o >>= 1) v += __shfl_down(v, o, 64);
  if ((t & 63) == 0) sm[t >> 6] = v;
  __syncthreads();
  if (t == 0) out[0] = (sm[0] + sm[1] + sm[2] + sm[3]) * (1.0f / BATCH);
}

// -------------------------------- fallback cleanup: copy front rows afterwards
__global__ void copy_front(const float* __restrict__ src,
                           float* __restrict__ dst, int n4) {
  int idx = blockIdx.x * blockDim.x + threadIdx.x;
  int stride = gridDim.x * blockDim.x;
  for (int i = idx; i < n4; i += stride) {
    f32x4 v = *(const f32x4*)&src[(size_t)i * 4];
    float* d = &dst[(size_t)i * 4];
    d[0] = v[0]; d[1] = v[1]; d[2] = v[2]; d[3] = v[3];
  }
}

// --------------------------------------------- momentum update of touched rows
__global__ __launch_bounds__(256) void update_rows(
    const float* __restrict__ f, const float* __restrict__ features,
    const int* __restrict__ indexes, float* __restrict__ outF) {
  __shared__ float sred[16];
  const int i = blockIdx.x;
  const int row = indexes[i];
  for (int i2 = i + 1; i2 < BATCH; ++i2)
    if (indexes[i2] == row) return;          // last occurrence wins
  const int t = threadIdx.x;
  float ss = 0.f;
  for (int d = t; d < DIM; d += 256) {
    float u = 0.2f * features[(size_t)row * DIM + d] + 0.8f * f[(size_t)i * DIM + d];
    ss += u * u;
  }
  ss = block_sum(ss, sred);
  float nrm = fmaxf(sqrtf(ss), 1e-12f);
  for (int d = t; d < DIM; d += 256) {
    float u = 0.2f * features[(size_t)row * DIM + d] + 0.8f * f[(size_t)i * DIM + d];
    outF[(size_t)row * DIM + d] = u / nrm;
  }
}

// ------------------------------------------------------------------- launcher
extern "C" void kernel_launch(void* const* d_in, const int* in_sizes, int n_in,
                              void* d_out, int out_size, void* d_ws, size_t ws_size,
                              hipStream_t stream) {
  (void)in_sizes; (void)n_in; (void)out_size;
  const float* f        = (const float*)d_in[0];
  const float* f_nv     = (const float*)d_in[1];
  const float* features = (const float*)d_in[2];
  const int*   labels   = (const int*)d_in[3];
  const int*   indexes  = (const int*)d_in[4];
  float* out = (float*)d_out;

  // scratch: mat_sim 32MB + row_loss + Abf 1MB + fbf16 64MB; prefer d_ws
  const size_t n_mat = (size_t)BATCH * NROWS;           // 8,388,608 floats
  const size_t n_scratch = n_mat + 256 + 262144 + (size_t)NROWS * DIM / 2;
  float* mat_sim;
  float* row_loss;
  uint32_t* Abf;
  uint32_t* fbf16;
  int skip_rows;
  bool use_ws = (d_ws != nullptr) && (ws_size >= n_scratch * sizeof(float));
  if (use_ws) {
    mat_sim = (float*)d_ws;
    skip_rows = 0;
  } else {
    mat_sim = out + 4;
    skip_rows = 12544;  // scratch occupies outF rows < 12544; fixed by copy_front
  }
  row_loss = mat_sim + n_mat;
  Abf = (uint32_t*)(row_loss + 256);
  fbf16 = Abf + 262144;

  // kg1..kg3 = split(key(42), 3), partitionable threefry
  uint32_t c[6];
  { uint32_t a, b;
    tf2x32(0u, 42u, 0u, 0u, a, b); c[0] = a; c[1] = b;
    tf2x32(0u, 42u, 0u, 1u, a, b); c[2] = a; c[3] = b;
    tf2x32(0u, 42u, 0u, 2u, a, b); c[4] = a; c[5] = b; }

  cvtA<<<dim3(256), dim3(256), 0, stream>>>(f_nv, Abf);
  prep<<<dim3(2048), dim3(256), 0, stream>>>(features, out + 1, fbf16, skip_rows);
  gemm_bf<<<dim3(2 * NROWS / 128), dim3(256), 0, stream>>>(Abf, fbf16, mat_sim);
  sample_loss<<<dim3(BATCH), dim3(1024), 0, stream>>>(
      f, f_nv, features, labels, indexes, mat_sim, row_loss,
      c[0], c[1], c[2], c[3], c[4], c[5]);
  finalize_loss<<<dim3(1), dim3(256), 0, stream>>>(row_loss, out);
  if (!use_ws) {
    copy_front<<<dim3(2048), dim3(256), 0, stream>>>(
        features, out + 1, 12544 * DIM / 4);
  }
  update_rows<<<dim3(BATCH), dim3(256), 0, stream>>>(f, features, indexes, out + 1);
}

// Round 13
// 301.399 us; speedup vs baseline: 1.1742x; 1.1202x over previous
//
#include <hip/hip_runtime.h>
#include <stdint.h>

#define TEMP      0.07f
#define BATCH     256
#define NROWS     32768
#define DIM       2048
#define KNEG      8192

typedef __attribute__((ext_vector_type(8))) short bf16x8;
typedef __attribute__((ext_vector_type(4))) float f32x4;

// ---------------------------------------------------------------- threefry2x32
__host__ __device__ inline void tf2x32(uint32_t ka, uint32_t kb,
                                       uint32_t x0, uint32_t x1,
                                       uint32_t& o0, uint32_t& o1) {
  uint32_t ks2 = ka ^ kb ^ 0x1BD11BDAu;
#define TFR(r) { x0 += x1; x1 = (x1 << r) | (x1 >> (32 - r)); x1 ^= x0; }
  x0 += ka; x1 += kb;
  TFR(13) TFR(15) TFR(26) TFR(6)
  x0 += kb;  x1 += ks2 + 1u;
  TFR(17) TFR(29) TFR(16) TFR(24)
  x0 += ks2; x1 += ka + 2u;
  TFR(13) TFR(15) TFR(26) TFR(6)
  x0 += ka;  x1 += kb + 3u;
  TFR(17) TFR(29) TFR(16) TFR(24)
  x0 += kb;  x1 += ks2 + 4u;
  TFR(13) TFR(15) TFR(26) TFR(6)
  x0 += ks2; x1 += ka + 5u;
#undef TFR
  o0 = x0; o1 = x1;
}

// partitionable threefry (JAX >= 0.4.36): bits = out0 ^ out1, counter = (0, q)
__device__ inline uint32_t ubits_at(uint32_t ka, uint32_t kb, uint32_t q) {
  uint32_t a, b; tf2x32(ka, kb, 0u, q, a, b);
  return (a ^ b) >> 9;
}

// ---------------------------------------------------------------- block reduce
__device__ inline float block_sum(float v, float* sm) {
  __syncthreads();
  const int lane = threadIdx.x & 63;
  const int w = threadIdx.x >> 6;
  const int nw = blockDim.x >> 6;
  for (int o = 32; o; o >>= 1) v += __shfl_down(v, o, 64);
  if (lane == 0) sm[w] = v;
  __syncthreads();
  if (w == 0) {
    float x = (lane < nw) ? sm[lane] : 0.f;
    for (int o = 8; o; o >>= 1) x += __shfl_down(x, o, 64);
    if (lane == 0) sm[0] = x;
  }
  __syncthreads();
  return sm[0];
}

__device__ inline uint32_t pk2(float a, float b) {  // 2x fp32 -> packed bf16 (RNE)
  uint32_t ua = __float_as_uint(a), ub = __float_as_uint(b);
  ua = (ua + 0x7FFFu + ((ua >> 16) & 1u)) >> 16;
  ub = (ub + 0x7FFFu + ((ub >> 16) & 1u)) >> 16;
  return ua | (ub << 16);
}

// -------------------------- pack f_nv into bf16 MFMA A-fragment layout (1 MB)
// Fragment tile (mt,kt): 1 KB, lane l holds rows mt*16+(l&15), k kt*32+(l>>4)*8.
__global__ __launch_bounds__(256) void cvtA(const float* __restrict__ A,
                                            uint32_t* __restrict__ Abf) {
  const int t = threadIdx.x;
  const int w = blockIdx.x * 4 + (t >> 6);   // 1024 fragment tiles
  const int l = t & 63;
  const int mt = w >> 6, kt = w & 63;
  const float* src = &A[(size_t)(mt * 16 + (l & 15)) * DIM + kt * 32 + (l >> 4) * 8];
  float4 f0 = *(const float4*)src;
  float4 f1 = *(const float4*)(src + 4);
  *(uint4*)(Abf + (size_t)w * 256 + l * 4) =
      make_uint4(pk2(f0.x, f0.y), pk2(f0.z, f0.w), pk2(f1.x, f1.y), pk2(f1.z, f1.w));
}

// ------------------------------------------------------- async LDS staging DMA
__device__ inline void gll16(const float* g, float* l) {
  __builtin_amdgcn_global_load_lds(
      (const __attribute__((address_space(1))) uint32_t*)g,
      (__attribute__((address_space(3))) uint32_t*)l, 16, 0, 0);
}

// ---------------- heterogeneous co-scheduled kernel (r8 base) + split-K GEMM
// 512 groups x 4 blocks: roles 0,1 = stream-copy 32 feature rows each to outF
// (primes L3); roles 2,3 = GEMM over the same 64-row B-panel, K-half (role-2).
// Split-K halves each GEMM block's serial barrier chain (16 steps) and doubles
// GEMM block parallelism; partials land in matp[kh] and are summed by
// sample_loss during its existing read pass.
__global__ __launch_bounds__(256, 4) void mega(
    const uint32_t* __restrict__ Abf,  // packed f_nv bf16 A-fragments
    const float* __restrict__ Bfeat,   // features [32768][2048]
    float* __restrict__ matp,          // 2 x [256][32768] partial products
    float* __restrict__ outF,          // out+1 (new_features)
    int skip) {                        // copy only feature rows >= skip
  __shared__ float Bs[64 * 64];        // 16 KiB fp32 B-tile (GEMM roles)
  const int role = blockIdx.x & 3;
  const int g = blockIdx.x >> 2;       // 512 groups: rows/cols g*64..g*64+63
  const int t = threadIdx.x;

  if (role < 2) {
    // ---------------- streaming copy of 32 full rows (256 KB) ----------------
    const int r0 = g * 64 + role * 32;
    const float* src = Bfeat + (size_t)r0 * DIM;
    float* dst = outF + (size_t)r0 * DIM;
    const int total4 = 32 * DIM / 4;           // 16384 f32x4
#pragma unroll 4
    for (int i = t; i < total4; i += 256) {
      const int gr = r0 + (i >> 9);            // i*4/DIM
      f32x4 v = *(const f32x4*)(src + (size_t)i * 4);
      if (gr >= skip)
        *(f32x4*)(dst + (size_t)i * 4) = v;
    }
    return;
  }

  // ------------------------------- GEMM block ------------------------------
  const int kh = role - 2;             // K-half: [kh*1024, kh*1024+1024)
  const int l = t & 63, w = t >> 6;
  f32x4 acc[4][4] = {};

  for (int t0 = 0; t0 < 16; ++t0) {
    const int k0 = kh * 1024 + t0 * 64;
    __syncthreads();                       // previous tile consumed
    // stage B tile 64x64 fp32: 4 gll per wave, LDS linear, src granule-XOR'd
#pragma unroll
    for (int i = 0; i < 4; ++i) {
      const int ii = w * 4 + i;            // 16 x 1KB
      const int r = 4 * ii + (l >> 4);     // tile row
      const int gs = (l & 15) ^ (r & 7);   // global granule for LDS slot l&15
      gll16(&Bfeat[(size_t)(g * 64 + r) * DIM + k0 + gs * 4],
            &Bs[ii * 256]);
    }
    __syncthreads();                       // tile ready (compiler drains)
#pragma unroll
    for (int kk = 0; kk < 2; ++kk) {
      bf16x8 af[4];
#pragma unroll
      for (int m = 0; m < 4; ++m)
        af[m] = *(const bf16x8*)(Abf +
            ((size_t)((w * 4 + m) * 64 + kh * 32 + t0 * 2 + kk) * 64 + l) * 4);
      bf16x8 bfr[4];
#pragma unroll
      for (int n = 0; n < 4; ++n) {
        const int row = n * 16 + (l & 15);
        const int b2 = 2 * (kk * 4 + (l >> 4));
        const int s = row & 7;
        f32x4 lo = *(const f32x4*)&Bs[row * 64 + (b2 ^ s) * 4];
        f32x4 hi = *(const f32x4*)&Bs[row * 64 + ((b2 + 1) ^ s) * 4];
        uint32_t c0, c1, c2, c3;
        asm("v_cvt_pk_bf16_f32 %0, %1, %2" : "=v"(c0) : "v"(lo[0]), "v"(lo[1]));
        asm("v_cvt_pk_bf16_f32 %0, %1, %2" : "=v"(c1) : "v"(lo[2]), "v"(lo[3]));
        asm("v_cvt_pk_bf16_f32 %0, %1, %2" : "=v"(c2) : "v"(hi[0]), "v"(hi[1]));
        asm("v_cvt_pk_bf16_f32 %0, %1, %2" : "=v"(c3) : "v"(hi[2]), "v"(hi[3]));
        union { uint32_t u[4]; bf16x8 b; } cv;
        cv.u[0] = c0; cv.u[1] = c1; cv.u[2] = c2; cv.u[3] = c3;
        bfr[n] = cv.b;
      }
#pragma unroll
      for (int m = 0; m < 4; ++m)
#pragma unroll
        for (int n = 0; n < 4; ++n)
          acc[m][n] = __builtin_amdgcn_mfma_f32_16x16x32_bf16(
              af[m], bfr[n], acc[m][n], 0, 0, 0);
    }
  }

  // epilogue: partial-C write
  float* Cp = matp + (size_t)kh * BATCH * NROWS;
#pragma unroll
  for (int m = 0; m < 4; ++m)
#pragma unroll
    for (int n = 0; n < 4; ++n) {
      const int row0 = w * 64 + m * 16 + (l >> 4) * 4;
      const int col = g * 64 + n * 16 + (l & 15);
#pragma unroll
      for (int r = 0; r < 4; ++r)
        Cp[(size_t)(row0 + r) * NROWS + col] = acc[m][n][r];
    }
}

// -------------------------------------------------- per-row sampling + CE loss
__global__ __launch_bounds__(1024) void sample_loss(
    const float* __restrict__ f, const float* __restrict__ f_nv,
    const float* __restrict__ features, const int* __restrict__ labels,
    const int* __restrict__ indexes,
    const float* __restrict__ p0, const float* __restrict__ p1,
    float* __restrict__ row_loss,
    uint32_t k1a, uint32_t k1b, uint32_t k2a, uint32_t k2b,
    uint32_t k3a, uint32_t k3b) {
  __shared__ uint32_t keys[NROWS];      // 128 KiB sortable uniform bits
  __shared__ uint32_t hist4[4][256];    // privatized histograms
  __shared__ uint32_t hist[256];
  __shared__ unsigned long long am1, am2;
  __shared__ int tie_j[128];
  __shared__ int tie_cnt;
  __shared__ float sred[16];
  __shared__ float swm[16], sws[16];
  __shared__ uint32_t bc_prefix, bc_rem;
  __shared__ int blab_s;

  const int t = threadIdx.x;
  const int i = blockIdx.x;
  const size_t mbase = (size_t)i * NROWS;

  if (t == 0) {
    blab_s = labels[indexes[i]];
    am1 = 0ull; am2 = 0ull; tie_cnt = 0;
  }
  ((uint32_t*)hist4)[t] = 0u;           // pass-0 histogram built during phase 1
  __syncthreads();
  const int blab = blab_s;
  const int hsel = t >> 8;

#pragma unroll 2
  for (int s = 0; s < NROWS / 1024; ++s) {
    int j = t + 1024 * s;
    uint32_t q = (uint32_t)i * NROWS + (uint32_t)j;
    int lab = labels[j];
    uint32_t key;
    if (lab == blab) {
      key = 0u;
      unsigned long long lo = (unsigned long long)(uint32_t)(NROWS - 1 - j);
      uint32_t u1 = ubits_at(k1a, k1b, q);
      uint32_t u2 = ubits_at(k2a, k2b, q);
      atomicMax(&am1, ((unsigned long long)u1 << 32) | lo);
      atomicMax(&am2, ((unsigned long long)u2 << 32) | lo);
    } else {
      key = ubits_at(k3a, k3b, q);
    }
    keys[j] = key;
    atomicAdd(&hist4[hsel][key >> 15], 1u);
  }
  __syncthreads();

  const int jw = NROWS - 1 - (int)(unsigned)(am1 & 0xFFFFFFFFull);
  const int jp = NROWS - 1 - (int)(unsigned)(am2 & 0xFFFFFFFFull);

  const int bank = indexes[i];
  float d1 = 0.f, d2 = 0.f, d3 = 0.f;
  for (int d = t; d < DIM; d += 1024) {
    float fnv = f_nv[(size_t)i * DIM + d];
    d1 += fnv * features[(size_t)bank * DIM + d];
    d2 += f[(size_t)i * DIM + d] * features[(size_t)jw * DIM + d];
    d3 += fnv * features[(size_t)jp * DIM + d];
  }
  const float l_pos = block_sum(d1, sred);
  const float posw  = block_sum(d2, sred);
  const float posv  = block_sum(d3, sred);

  uint32_t prefix = 0, remaining = KNEG;
  const int shifts[3] = {15, 7, 0};
  const int nbits[3]  = {8, 8, 7};
  for (int p = 0; p < 3; ++p) {
    const int sh = shifts[p];
    const int nb = 1 << nbits[p];
    if (p) {
      ((uint32_t*)hist4)[t] = 0u;
      __syncthreads();
      for (int s = 0; s < NROWS / 1024; ++s) {
        int j = t + 1024 * s;
        uint32_t k = keys[j];
        if ((k >> (sh + nbits[p])) == prefix)
          atomicAdd(&hist4[hsel][(k >> sh) & (uint32_t)(nb - 1)], 1u);
      }
    }
    __syncthreads();
    if (t < nb) hist[t] = hist4[0][t] + hist4[1][t] + hist4[2][t] + hist4[3][t];
    __syncthreads();
    if (t == 0) {
      uint32_t c = 0; int b = nb - 1;
      for (;; --b) {
        c += hist[b];
        if (c >= remaining || b == 0) break;
      }
      bc_prefix = (prefix << nbits[p]) | (uint32_t)b;
      bc_rem = remaining - (c - hist[b]);
    }
    __syncthreads();
    prefix = bc_prefix; remaining = bc_rem;
  }
  const uint32_t T = prefix;
  const uint32_t need = remaining;

  float m = -INFINITY, ssum = 0.f;
  for (int s = 0; s < NROWS / 1024; ++s) {
    int j = t + 1024 * s;
    uint32_t k = keys[j];
    if (k > T) {
      float v = (p0[mbase + j] + p1[mbase + j]) / TEMP;
      if (v <= m) ssum += expf(v - m);
      else { ssum = ssum * expf(m - v) + 1.0f; m = v; }
    } else if (k == T) {
      int p = atomicAdd(&tie_cnt, 1);
      if (p < 128) tie_j[p] = j;
    }
  }
  for (int o = 32; o; o >>= 1) {
    float m2 = __shfl_down(m, o, 64);
    float s2 = __shfl_down(ssum, o, 64);
    if (m2 > m) { ssum = ssum * expf(m - m2) + s2; m = m2; }
    else if (m2 != -INFINITY) ssum += s2 * expf(m2 - m);
  }
  if ((t & 63) == 0) { swm[t >> 6] = m; sws[t >> 6] = ssum; }
  __syncthreads();
  if (t < 64) {
    float mm = (t < 16) ? swm[t] : -INFINITY;
    float ss = (t < 16) ? sws[t] : 0.f;
    for (int o = 8; o; o >>= 1) {
      float m2 = __shfl_down(mm, o, 64);
      float s2 = __shfl_down(ss, o, 64);
      if (m2 > mm) { ss = ss * expf(mm - m2) + s2; mm = m2; }
      else if (m2 != -INFINITY) ss += s2 * expf(m2 - mm);
    }
    if (t == 0) { swm[0] = mm; sws[0] = ss; }
  }
  __syncthreads();

  if (t == 0) {
    float M = swm[0], S = sws[0];
    int tc = tie_cnt;
    if (tc <= 128) {
      for (int a2 = 1; a2 < tc; ++a2) {
        int v = tie_j[a2]; int b2 = a2 - 1;
        while (b2 >= 0 && tie_j[b2] > v) { tie_j[b2 + 1] = tie_j[b2]; --b2; }
        tie_j[b2 + 1] = v;
      }
      for (uint32_t r = 0; r < need; ++r) {
        float v = (p0[mbase + tie_j[r]] + p1[mbase + tie_j[r]]) / TEMP;
        if (v <= M) S += expf(v - M);
        else { S = S * expf(M - v) + 1.0f; M = v; }
      }
    } else {
      uint32_t taken = 0;
      for (int j = 0; j < NROWS && taken < need; ++j) {
        if (keys[j] == T) {
          float v = (p0[mbase + j] + p1[mbase + j]) / TEMP;
          if (v <= M) S += expf(v - M);
          else { S = S * expf(M - v) + 1.0f; M = v; }
          ++taken;
        }
      }
    }
    float lp = l_pos / TEMP, pv = posv / TEMP, pw = posw / TEMP;
    float L = 0.f;
    { float X = fmaxf(M, lp); L += X + logf(expf(lp - X) + S * expf(M - X)) - lp; }
    { float X = fmaxf(M, pv); L += X + logf(expf(pv - X) + S * expf(M - X)) - pv; }
    { float X = fmaxf(M, pw); L += X + logf(expf(pw - X) + S * expf(M - X)) - pw; }
    row_loss[i] = L;
  }
}

// ---------------------------------------------------------------- finalize loss
__global__ void finalize_loss(const float* __restrict__ row_loss,
                              float* __restrict__ out) {
  __shared__ float sm[4];
  int t = threadIdx.x;
  float v = row_loss[t];
  for (int o = 32; o; o >>= 1) v += __shfl_down(v, o, 64);
  if ((t & 63) == 0) sm[t >> 6] = v;
  __syncthreads();
  if (t == 0) out[0] = (sm[0] + sm[1] + sm[2] + sm[3]) * (1.0f / BATCH);
}

// -------------------------------- fallback cleanup: copy front rows afterwards
__global__ void copy_front(const float* __restrict__ src,
                           float* __restrict__ dst, int n4) {
  int idx = blockIdx.x * blockDim.x + threadIdx.x;
  int stride = gridDim.x * blockDim.x;
  for (int i = idx; i < n4; i += stride) {
    f32x4 v = *(const f32x4*)&src[(size_t)i * 4];
    float* d = &dst[(size_t)i * 4];
    d[0] = v[0]; d[1] = v[1]; d[2] = v[2]; d[3] = v[3];
  }
}

// --------------------------------------------- momentum update of touched rows
__global__ __launch_bounds__(256) void update_rows(
    const float* __restrict__ f, const float* __restrict__ features,
    const int* __restrict__ indexes, float* __restrict__ outF) {
  __shared__ float sred[16];
  const int i = blockIdx.x;
  const int row = indexes[i];
  for (int i2 = i + 1; i2 < BATCH; ++i2)
    if (indexes[i2] == row) return;          // last occurrence wins
  const int t = threadIdx.x;
  float ss = 0.f;
  for (int d = t; d < DIM; d += 256) {
    float u = 0.2f * features[(size_t)row * DIM + d] + 0.8f * f[(size_t)i * DIM + d];
    ss += u * u;
  }
  ss = block_sum(ss, sred);
  float nrm = fmaxf(sqrtf(ss), 1e-12f);
  for (int d = t; d < DIM; d += 256) {
    float u = 0.2f * features[(size_t)row * DIM + d] + 0.8f * f[(size_t)i * DIM + d];
    outF[(size_t)row * DIM + d] = u / nrm;
  }
}

// ------------------------------------------------------------------- launcher
extern "C" void kernel_launch(void* const* d_in, const int* in_sizes, int n_in,
                              void* d_out, int out_size, void* d_ws, size_t ws_size,
                              hipStream_t stream) {
  (void)in_sizes; (void)n_in; (void)out_size;
  const float* f        = (const float*)d_in[0];
  const float* f_nv     = (const float*)d_in[1];
  const float* features = (const float*)d_in[2];
  const int*   labels   = (const int*)d_in[3];
  const int*   indexes  = (const int*)d_in[4];
  float* out = (float*)d_out;

  // scratch: matp 2x33.5MB + row_loss + Abf 1MB; prefer d_ws
  const size_t n_mat = (size_t)BATCH * NROWS;                // 8,388,608 floats
  const size_t n_scratch = 2 * n_mat + 256 + 262144;         // 17,039,616
  float* matp;
  float* row_loss;
  uint32_t* Abf;
  int skip_rows;
  bool use_ws = (d_ws != nullptr) && (ws_size >= n_scratch * sizeof(float));
  if (use_ws) {
    matp = (float*)d_ws;
    skip_rows = 0;
  } else {
    matp = out + 4;
    skip_rows = 8321;   // ceil(17,039,616 / 2048): rows holding scratch
  }
  row_loss = matp + 2 * n_mat;
  Abf = (uint32_t*)(row_loss + 256);

  // kg1..kg3 = split(key(42), 3), partitionable threefry
  uint32_t c[6];
  { uint32_t a, b;
    tf2x32(0u, 42u, 0u, 0u, a, b); c[0] = a; c[1] = b;
    tf2x32(0u, 42u, 0u, 1u, a, b); c[2] = a; c[3] = b;
    tf2x32(0u, 42u, 0u, 2u, a, b); c[4] = a; c[5] = b; }

  cvtA<<<dim3(256), dim3(256), 0, stream>>>(f_nv, Abf);
  mega<<<dim3(4 * NROWS / 64), dim3(256), 0, stream>>>(
      Abf, features, matp, out + 1, skip_rows);
  sample_loss<<<dim3(BATCH), dim3(1024), 0, stream>>>(
      f, f_nv, features, labels, indexes, matp, matp + n_mat, row_loss,
      c[0], c[1], c[2], c[3], c[4], c[5]);
  finalize_loss<<<dim3(1), dim3(256), 0, stream>>>(row_loss, out);
  if (!use_ws) {
    copy_front<<<dim3(2048), dim3(256), 0, stream>>>(
        features, out + 1, 8321 * DIM / 4);
  }
  update_rows<<<dim3(BATCH), dim3(256), 0, stream>>>(f, features, indexes, out + 1);
}